// Round 3
// baseline (268.280 us; speedup 1.0000x reference)
//
#include <hip/hip_runtime.h>
#include <math.h>

#define BB 4
#define CC 256
#define HWN 4096

typedef __attribute__((ext_vector_type(8))) short short8;
typedef __attribute__((ext_vector_type(4))) float f32x4;
typedef unsigned short ushort_t;

__device__ __forceinline__ ushort_t f2bf(float f) {
    unsigned int u = __float_as_uint(f);
    unsigned int r = (u + 0x7FFFu + ((u >> 16) & 1u)) >> 16;   // RNE
    return (ushort_t)r;
}

// ---------------------------------------------------------------------------
// Convert projection weights fp32 -> bf16 (layout unchanged, [d][c]).
// ---------------------------------------------------------------------------
__global__ __launch_bounds__(256) void wconv_kernel(
    const float* __restrict__ q_w, const float* __restrict__ k_w,
    ushort_t* __restrict__ wq, ushort_t* __restrict__ wk)
{
    int i = blockIdx.x * 256 + threadIdx.x;   // 16384 threads
    #pragma unroll
    for (int r = 0; r < 4; r++) {
        int idx = i + r * 16384;              // CC*CC = 65536
        wq[idx] = f2bf(q_w[idx]);
        wk[idx] = f2bf(k_w[idx]);
    }
}

// ---------------------------------------------------------------------------
// MFMA projection: block = (b, 64-token tile); 4 waves x 16 tokens.
// A-fragments (tokens x c) built once via LDS transpose of feature, resident.
// d-loop: 16 d-tiles, B-frags from bf16 weights (L2-hot), 8+8 MFMAs (Q and K).
// Epilogue: +bias, Q pre-scaled by 1/sqrt(C), bf16 token-major store.
// ---------------------------------------------------------------------------
__global__ __launch_bounds__(256) void proj_kernel(
    const float* __restrict__ feature,
    const ushort_t* __restrict__ wq, const ushort_t* __restrict__ wk,
    const float* __restrict__ q_bias, const float* __restrict__ k_bias,
    ushort_t* __restrict__ qb, ushort_t* __restrict__ kb)
{
    int nt = blockIdx.x & 63;
    int b  = blockIdx.x >> 6;
    int n0 = nt * 64;

    int t = threadIdx.x;
    int w = t >> 6, lane = t & 63;
    int n16 = lane & 15, quad = lane >> 4;

    const float* F = feature + (size_t)b * CC * HWN;

    __shared__ float lf[32][66];   // [c-chunk 32][64 tokens], pad -> no 4-way conflicts

    // Build resident A fragments: A[m = w*16+n16][k = quad*8+j], 8 chunks of K=32
    short8 af[8];
    int cl = t >> 3, nl = (t & 7) * 8;
    int nrow = w * 16 + n16;
    for (int ch = 0; ch < 8; ch++) {
        const float* src = F + (size_t)(ch * 32 + cl) * HWN + n0 + nl;
        float4 v0 = *(const float4*)src;
        float4 v1 = *(const float4*)(src + 4);
        *(float2*)&lf[cl][nl]     = make_float2(v0.x, v0.y);
        *(float2*)&lf[cl][nl + 2] = make_float2(v0.z, v0.w);
        *(float2*)&lf[cl][nl + 4] = make_float2(v1.x, v1.y);
        *(float2*)&lf[cl][nl + 6] = make_float2(v1.z, v1.w);
        __syncthreads();
        short8 a;
        #pragma unroll
        for (int j = 0; j < 8; j++)
            a[j] = (short)f2bf(lf[quad * 8 + j][nrow]);
        af[ch] = a;
        __syncthreads();
    }

    ushort_t* qo = qb + (size_t)b * HWN * CC;
    ushort_t* ko = kb + (size_t)b * HWN * CC;
    int nbase = n0 + w * 16 + quad * 4;     // C/D rows: quad*4 + r

    for (int dt = 0; dt < 16; dt++) {
        int d0 = dt * 16;
        short8 bq[8], bk[8];
        #pragma unroll
        for (int c = 0; c < 8; c++) {
            size_t off = (size_t)(d0 + n16) * CC + c * 32 + quad * 8;
            bq[c] = *(const short8*)&wq[off];
            bk[c] = *(const short8*)&wk[off];
        }
        f32x4 aq = {0.f, 0.f, 0.f, 0.f};
        f32x4 ak = {0.f, 0.f, 0.f, 0.f};
        #pragma unroll
        for (int c = 0; c < 8; c++) {
            aq = __builtin_amdgcn_mfma_f32_16x16x32_bf16(af[c], bq[c], aq, 0, 0, 0);
            ak = __builtin_amdgcn_mfma_f32_16x16x32_bf16(af[c], bk[c], ak, 0, 0, 0);
        }
        float biq = q_bias[d0 + n16];
        float bik = k_bias[d0 + n16];
        #pragma unroll
        for (int r = 0; r < 4; r++) {
            qo[(size_t)(nbase + r) * CC + d0 + n16] = f2bf((aq[r] + biq) * 0.0625f);
            ko[(size_t)(nbase + r) * CC + d0 + n16] = f2bf(ak[r] + bik);
        }
    }
}

// ---------------------------------------------------------------------------
// MFMA attention: block = (b, 128-q tile, 512-key range); 4 waves x 32 q.
// Q pre-scaled by 1/sqrt(C) => exp(acc) directly. No-max softmax => s-split
// is additively exact via atomics.
// ---------------------------------------------------------------------------
__global__ __launch_bounds__(256) void attn_kernel(
    const ushort_t* __restrict__ qb, const ushort_t* __restrict__ kb,
    const float* __restrict__ flow,
    float* __restrict__ den_g, float* __restrict__ nx_g, float* __restrict__ ny_g)
{
    int id = blockIdx.x;
    int sr = id & 7;  id >>= 3;
    int qt = id & 31; id >>= 5;
    int b = id;

    int w    = threadIdx.x >> 6;
    int lane = threadIdx.x & 63;
    int n16  = lane & 15;
    int quad = lane >> 4;

    int q0    = qt * 128 + w * 32;
    int s_beg = sr * 512;
    int s_end = s_beg + 512;

    const ushort_t* Qb = qb + (size_t)b * HWN * CC;
    const ushort_t* Kb = kb + (size_t)b * HWN * CC;
    const float* fx = flow + (size_t)b * 2 * HWN;
    const float* fy = fx + HWN;

    short8 qf[2][8];
    #pragma unroll
    for (int tq = 0; tq < 2; tq++)
        #pragma unroll
        for (int c = 0; c < 8; c++)
            qf[tq][c] = *(const short8*)&Qb[(size_t)(q0 + tq * 16 + n16) * CC
                                            + c * 32 + quad * 8];

    float den[2][4], nxa[2][4], nya[2][4];
    #pragma unroll
    for (int tq = 0; tq < 2; tq++)
        #pragma unroll
        for (int r = 0; r < 4; r++) { den[tq][r] = 0.f; nxa[tq][r] = 0.f; nya[tq][r] = 0.f; }

    short8 kf[8], kf2[8];
    #pragma unroll
    for (int c = 0; c < 8; c++)
        kf[c] = *(const short8*)&Kb[(size_t)(s_beg + n16) * CC + c * 32 + quad * 8];

    for (int s0 = s_beg; s0 < s_end; s0 += 16) {
        int sp = (s0 + 16 < s_end) ? (s0 + 16) : s_beg;  // uniform, in-bounds
        #pragma unroll
        for (int c = 0; c < 8; c++)
            kf2[c] = *(const short8*)&Kb[(size_t)(sp + n16) * CC + c * 32 + quad * 8];

        f32x4 acc0 = {0.f, 0.f, 0.f, 0.f};
        f32x4 acc1 = {0.f, 0.f, 0.f, 0.f};
        #pragma unroll
        for (int c = 0; c < 8; c++) {
            acc0 = __builtin_amdgcn_mfma_f32_16x16x32_bf16(qf[0][c], kf[c], acc0, 0, 0, 0);
            acc1 = __builtin_amdgcn_mfma_f32_16x16x32_bf16(qf[1][c], kf[c], acc1, 0, 0, 0);
        }

        float vx = fx[s0 + n16];
        float vy = fy[s0 + n16];
        #pragma unroll
        for (int r = 0; r < 4; r++) {
            float p0 = __expf(acc0[r]);
            float p1 = __expf(acc1[r]);
            den[0][r] += p0;            den[1][r] += p1;
            nxa[0][r] = fmaf(p0, vx, nxa[0][r]);  nxa[1][r] = fmaf(p1, vx, nxa[1][r]);
            nya[0][r] = fmaf(p0, vy, nya[0][r]);  nya[1][r] = fmaf(p1, vy, nya[1][r]);
        }

        #pragma unroll
        for (int c = 0; c < 8; c++) kf[c] = kf2[c];
    }

    #pragma unroll
    for (int tq = 0; tq < 2; tq++)
        #pragma unroll
        for (int r = 0; r < 4; r++) {
            #pragma unroll
            for (int off = 8; off >= 1; off >>= 1) {
                den[tq][r] += __shfl_down(den[tq][r], off, 16);
                nxa[tq][r] += __shfl_down(nxa[tq][r], off, 16);
                nya[tq][r] += __shfl_down(nya[tq][r], off, 16);
            }
        }
    if (n16 == 0) {
        #pragma unroll
        for (int tq = 0; tq < 2; tq++)
            #pragma unroll
            for (int r = 0; r < 4; r++) {
                int qrow = q0 + tq * 16 + quad * 4 + r;
                int gi = b * HWN + qrow;
                atomicAdd(&den_g[gi], den[tq][r]);
                atomicAdd(&nx_g[gi],  nxa[tq][r]);
                atomicAdd(&ny_g[gi],  nya[tq][r]);
            }
    }
}

// ---------------------------------------------------------------------------
__global__ __launch_bounds__(256) void finalize_kernel(
    const float* __restrict__ den_g, const float* __restrict__ nx_g,
    const float* __restrict__ ny_g, float* __restrict__ out)
{
    int idx = blockIdx.x * 256 + threadIdx.x;  // b*HW + n
    int b = idx >> 12, n = idx & 4095;
    float inv = 1.0f / den_g[idx];
    out[(size_t)b * 2 * HWN + n]       = nx_g[idx] * inv;
    out[(size_t)b * 2 * HWN + HWN + n] = ny_g[idx] * inv;
}

extern "C" void kernel_launch(void* const* d_in, const int* in_sizes, int n_in,
                              void* d_out, int out_size, void* d_ws, size_t ws_size,
                              hipStream_t stream) {
    const float* feature = (const float*)d_in[0];
    const float* flow    = (const float*)d_in[1];
    const float* q_w     = (const float*)d_in[2];
    const float* q_b     = (const float*)d_in[3];
    const float* k_w     = (const float*)d_in[4];
    const float* k_b     = (const float*)d_in[5];
    float* out = (float*)d_out;

    ushort_t* qb = (ushort_t*)d_ws;                         // [B][HW][C] bf16
    ushort_t* kb = qb + (size_t)BB * HWN * CC;              // [B][HW][C] bf16
    ushort_t* wq = kb + (size_t)BB * HWN * CC;              // [C][C] bf16
    ushort_t* wk = wq + (size_t)CC * CC;
    float* den = (float*)(wk + (size_t)CC * CC);            // [B][HW]
    float* nx  = den + (size_t)BB * HWN;
    float* ny  = nx + (size_t)BB * HWN;

    hipMemsetAsync(den, 0, (size_t)3 * BB * HWN * sizeof(float), stream);
    wconv_kernel<<<64, 256, 0, stream>>>(q_w, k_w, wq, wk);
    proj_kernel<<<256, 256, 0, stream>>>(feature, wq, wk, q_b, k_b, qb, kb);
    attn_kernel<<<1024, 256, 0, stream>>>(qb, kb, flow, den, nx, ny);
    finalize_kernel<<<64, 256, 0, stream>>>(den, nx, ny, out);
}

// Round 4
// 191.871 us; speedup vs baseline: 1.3982x; 1.3982x over previous
//
#include <hip/hip_runtime.h>
#include <math.h>

#define BB 4
#define CC 256
#define HWN 4096
#define NTOK 16384                 // BB*HWN
#define SCQ 0.09016844136f         // (1/sqrt(256)) * log2(e)

typedef __attribute__((ext_vector_type(8))) short short8;
typedef __attribute__((ext_vector_type(4))) float f32x4;
typedef unsigned short ushort_t;

__device__ __forceinline__ ushort_t f2bf(float f) {
    unsigned int u = __float_as_uint(f);
    unsigned int r = (u + 0x7FFFu + ((u >> 16) & 1u)) >> 16;   // RNE
    return (ushort_t)r;
}
__device__ __forceinline__ unsigned int pack2(float a, float b) {
    return (unsigned int)f2bf(a) | ((unsigned int)f2bf(b) << 16);
}

// ---------------------------------------------------------------------------
// Weights fp32 -> bf16, [d][c] layout kept. Q weights pre-scaled by
// (1/sqrt(C))*log2(e) so attention can use raw exp2.
// ---------------------------------------------------------------------------
__global__ __launch_bounds__(256) void wconv_kernel(
    const float* __restrict__ q_w, const float* __restrict__ k_w,
    ushort_t* __restrict__ wq, ushort_t* __restrict__ wk)
{
    int i = (blockIdx.x * 256 + threadIdx.x) * 8;   // grid 32 -> 65536 elems
    float4 a = *(const float4*)&q_w[i];
    float4 b = *(const float4*)&q_w[i + 4];
    uint4 o;
    o.x = pack2(a.x * SCQ, a.y * SCQ);
    o.y = pack2(a.z * SCQ, a.w * SCQ);
    o.z = pack2(b.x * SCQ, b.y * SCQ);
    o.w = pack2(b.z * SCQ, b.w * SCQ);
    *(uint4*)&wq[i] = o;
    a = *(const float4*)&k_w[i];
    b = *(const float4*)&k_w[i + 4];
    o.x = pack2(a.x, a.y); o.y = pack2(a.z, a.w);
    o.z = pack2(b.x, b.y); o.w = pack2(b.z, b.w);
    *(uint4*)&wk[i] = o;
}

// ---------------------------------------------------------------------------
// Feature transpose: [b][c][tok] fp32 -> ft[b*HW + tok][c] bf16.
// 64c x 64tok tile per block, grid 1024.
// ---------------------------------------------------------------------------
__global__ __launch_bounds__(256) void tconv_kernel(
    const float* __restrict__ feature, ushort_t* __restrict__ ft)
{
    int id = blockIdx.x;
    int tb = id & 63; id >>= 6;
    int cb = id & 3;  id >>= 2;
    int b  = id;
    int t = threadIdx.x;

    __shared__ float lt[64][68];

    const float* F = feature + ((size_t)(b * CC + cb * 64)) * HWN + tb * 64;
    int cl = t >> 2, tg = (t & 3) * 16;
    const float* src = F + (size_t)cl * HWN + tg;
    *(float4*)&lt[cl][tg]      = *(const float4*)(src);
    *(float4*)&lt[cl][tg + 4]  = *(const float4*)(src + 4);
    *(float4*)&lt[cl][tg + 8]  = *(const float4*)(src + 8);
    *(float4*)&lt[cl][tg + 12] = *(const float4*)(src + 12);
    __syncthreads();

    int tok = t >> 2, c16 = (t & 3) * 16;
    uint4 o0, o1;
    o0.x = pack2(lt[c16 + 0][tok],  lt[c16 + 1][tok]);
    o0.y = pack2(lt[c16 + 2][tok],  lt[c16 + 3][tok]);
    o0.z = pack2(lt[c16 + 4][tok],  lt[c16 + 5][tok]);
    o0.w = pack2(lt[c16 + 6][tok],  lt[c16 + 7][tok]);
    o1.x = pack2(lt[c16 + 8][tok],  lt[c16 + 9][tok]);
    o1.y = pack2(lt[c16 + 10][tok], lt[c16 + 11][tok]);
    o1.z = pack2(lt[c16 + 12][tok], lt[c16 + 13][tok]);
    o1.w = pack2(lt[c16 + 14][tok], lt[c16 + 15][tok]);
    ushort_t* O = ft + ((size_t)(b * HWN + tb * 64 + tok)) * CC + cb * 64 + c16;
    *(uint4*)&O[0] = o0;
    *(uint4*)&O[8] = o1;
}

// ---------------------------------------------------------------------------
// MFMA projection, no LDS/barriers: block = 64 tokens x 128 d, computes Q AND K.
// A = weight rows (m=d), B = token rows (n=tok) -> C rows are d-contiguous
// => dense ushort4 stores. Grid 512, 4 waves (each wave 32 d).
// ---------------------------------------------------------------------------
__global__ __launch_bounds__(256) void proj_kernel(
    const ushort_t* __restrict__ ft,
    const ushort_t* __restrict__ wq, const ushort_t* __restrict__ wk,
    const float* __restrict__ q_bias, const float* __restrict__ k_bias,
    ushort_t* __restrict__ qb, ushort_t* __restrict__ kb)
{
    int id = blockIdx.x;
    int tt = id & 255;             // token tile (64), b folded
    int dh = id >> 8;              // d half (128)
    int t = threadIdx.x, w = t >> 6, lane = t & 63;
    int n16 = lane & 15, quad = lane >> 4;
    int n0 = tt * 64;

    #pragma unroll
    for (int dti = 0; dti < 2; dti++) {
        int d0 = dh * 128 + w * 32 + dti * 16;

        short8 aq[8], ak[8];
        #pragma unroll
        for (int c = 0; c < 8; c++) {
            size_t off = (size_t)(d0 + n16) * CC + c * 32 + quad * 8;
            aq[c] = *(const short8*)&wq[off];
            ak[c] = *(const short8*)&wk[off];
        }
        float bqv[4], bkv[4];
        #pragma unroll
        for (int r = 0; r < 4; r++) {
            bqv[r] = q_bias[d0 + quad * 4 + r] * SCQ;
            bkv[r] = k_bias[d0 + quad * 4 + r];
        }

        #pragma unroll
        for (int bt = 0; bt < 4; bt++) {
            f32x4 cq = {0.f, 0.f, 0.f, 0.f};
            f32x4 ck = {0.f, 0.f, 0.f, 0.f};
            #pragma unroll
            for (int c = 0; c < 8; c++) {
                short8 bf = *(const short8*)&ft[(size_t)(n0 + bt * 16 + n16) * CC
                                                + c * 32 + quad * 8];
                cq = __builtin_amdgcn_mfma_f32_16x16x32_bf16(aq[c], bf, cq, 0, 0, 0);
                ck = __builtin_amdgcn_mfma_f32_16x16x32_bf16(ak[c], bf, ck, 0, 0, 0);
            }
            size_t row = (size_t)(n0 + bt * 16 + n16) * CC + d0 + quad * 4;
            ushort4 oq, ok;
            oq.x = f2bf(cq[0] + bqv[0]); oq.y = f2bf(cq[1] + bqv[1]);
            oq.z = f2bf(cq[2] + bqv[2]); oq.w = f2bf(cq[3] + bqv[3]);
            ok.x = f2bf(ck[0] + bkv[0]); ok.y = f2bf(ck[1] + bkv[1]);
            ok.z = f2bf(ck[2] + bkv[2]); ok.w = f2bf(ck[3] + bkv[3]);
            *(ushort4*)&qb[row] = oq;
            *(ushort4*)&kb[row] = ok;
        }
    }
}

// ---------------------------------------------------------------------------
// Flash-style MFMA attention. Block = (b, 128-q, 512-key range), 4 waves.
// K-tile (64 keys x 256d = 32 KB) staged via global_load_lds with XOR swizzle
// (granule j ^= r&31) so ds_read_b128 fragments are conflict-free; shared by
// all 4 waves. Q pre-scaled by (1/16)*log2e => p = exp2(acc). No-max softmax
// => key-split additively exact via atomics.
// ---------------------------------------------------------------------------
__global__ __launch_bounds__(256) void attn_kernel(
    const ushort_t* __restrict__ qb, const ushort_t* __restrict__ kb,
    const float* __restrict__ flow,
    float* __restrict__ den_g, float* __restrict__ nx_g, float* __restrict__ ny_g)
{
    int id = blockIdx.x;
    int sr = id & 7;  id >>= 3;
    int qt = id & 31; id >>= 5;
    int b = id;

    int t = threadIdx.x;
    int w = t >> 6, lane = t & 63;
    int n16 = lane & 15, quad = lane >> 4;

    int q0 = qt * 128 + w * 32;
    int s_beg = sr * 512;

    const ushort_t* Qb = qb + (size_t)b * HWN * CC;
    const ushort_t* Kb = kb + (size_t)b * HWN * CC;

    __shared__ __align__(16) ushort_t lk[16384];   // 32 KB swizzled K tile
    __shared__ float lflow[1024];                  // 512 vx + 512 vy

    const float* fx = flow + (size_t)b * 2 * HWN;
    const float* fy = fx + HWN;
    for (int j = t; j < 512; j += 256) {
        lflow[j]       = fx[s_beg + j];
        lflow[512 + j] = fy[s_beg + j];
    }

    short8 qf[2][8];
    #pragma unroll
    for (int tq = 0; tq < 2; tq++)
        #pragma unroll
        for (int c = 0; c < 8; c++)
            qf[tq][c] = *(const short8*)&Qb[(size_t)(q0 + tq * 16 + n16) * CC
                                            + c * 32 + quad * 8];

    // staging source offsets (swizzled), loop-invariant
    int srcoff[8];
    #pragma unroll
    for (int i = 0; i < 8; i++) {
        int G = i * 256 + t;
        int r = G >> 5, j = G & 31;
        srcoff[i] = (r * 32 + (j ^ (r & 31))) * 16;
    }
    // per-c swizzled read offsets (even-bt form); odd bt XORs bit8 (256B)
    int p16[8];
    #pragma unroll
    for (int c = 0; c < 8; c++)
        p16[c] = (((c * 4 + quad) ^ n16) & 31) * 16;

    float den[2][4], nxa[2][4], nya[2][4];
    #pragma unroll
    for (int tq = 0; tq < 2; tq++)
        #pragma unroll
        for (int r = 0; r < 4; r++) { den[tq][r] = 0.f; nxa[tq][r] = 0.f; nya[tq][r] = 0.f; }

    for (int s0 = 0; s0 < 512; s0 += 64) {
        __syncthreads();   // LDS free (prev reads done; also covers lflow writes)
        const char* gsrc = (const char*)(Kb + (size_t)(s_beg + s0) * CC);
        char* ldst = (char*)lk + t * 16;
        #pragma unroll
        for (int i = 0; i < 8; i++) {
            __builtin_amdgcn_global_load_lds(
                (const __attribute__((address_space(1))) unsigned int*)(gsrc + srcoff[i]),
                (__attribute__((address_space(3))) unsigned int*)(ldst + i * 4096),
                16, 0, 0);
        }
        __syncthreads();   // drain staging

        #pragma unroll
        for (int bt = 0; bt < 4; bt++) {
            int rbase = (bt * 16 + n16) * 512;     // key-row byte base
            int x16   = (bt & 1) ? 256 : 0;        // swizzle bit4 flip for odd bt
            f32x4 a0 = {0.f, 0.f, 0.f, 0.f};
            f32x4 a1 = {0.f, 0.f, 0.f, 0.f};
            #pragma unroll
            for (int c = 0; c < 8; c++) {
                short8 kf = *(const short8*)((const char*)lk + rbase + (p16[c] ^ x16));
                a0 = __builtin_amdgcn_mfma_f32_16x16x32_bf16(qf[0][c], kf, a0, 0, 0, 0);
                a1 = __builtin_amdgcn_mfma_f32_16x16x32_bf16(qf[1][c], kf, a1, 0, 0, 0);
            }
            float vx = lflow[s0 + bt * 16 + n16];
            float vy = lflow[512 + s0 + bt * 16 + n16];
            #pragma unroll
            for (int r = 0; r < 4; r++) {
                float p0 = exp2f(a0[r]);
                float p1 = exp2f(a1[r]);
                den[0][r] += p0;                      den[1][r] += p1;
                nxa[0][r] = fmaf(p0, vx, nxa[0][r]);  nxa[1][r] = fmaf(p1, vx, nxa[1][r]);
                nya[0][r] = fmaf(p0, vy, nya[0][r]);  nya[1][r] = fmaf(p1, vy, nya[1][r]);
            }
        }
    }

    #pragma unroll
    for (int tq = 0; tq < 2; tq++)
        #pragma unroll
        for (int r = 0; r < 4; r++) {
            #pragma unroll
            for (int off = 8; off >= 1; off >>= 1) {
                den[tq][r] += __shfl_down(den[tq][r], off, 16);
                nxa[tq][r] += __shfl_down(nxa[tq][r], off, 16);
                nya[tq][r] += __shfl_down(nya[tq][r], off, 16);
            }
        }
    if (n16 == 0) {
        #pragma unroll
        for (int tq = 0; tq < 2; tq++)
            #pragma unroll
            for (int r = 0; r < 4; r++) {
                int qrow = q0 + tq * 16 + quad * 4 + r;
                int gi = b * HWN + qrow;
                atomicAdd(&den_g[gi], den[tq][r]);
                atomicAdd(&nx_g[gi],  nxa[tq][r]);
                atomicAdd(&ny_g[gi],  nya[tq][r]);
            }
    }
}

// ---------------------------------------------------------------------------
__global__ __launch_bounds__(256) void finalize_kernel(
    const float* __restrict__ den_g, const float* __restrict__ nx_g,
    const float* __restrict__ ny_g, float* __restrict__ out)
{
    int idx = blockIdx.x * 256 + threadIdx.x;  // b*HW + n
    int b = idx >> 12, n = idx & 4095;
    float inv = 1.0f / den_g[idx];
    out[(size_t)b * 2 * HWN + n]       = nx_g[idx] * inv;
    out[(size_t)b * 2 * HWN + HWN + n] = ny_g[idx] * inv;
}

extern "C" void kernel_launch(void* const* d_in, const int* in_sizes, int n_in,
                              void* d_out, int out_size, void* d_ws, size_t ws_size,
                              hipStream_t stream) {
    const float* feature = (const float*)d_in[0];
    const float* flow    = (const float*)d_in[1];
    const float* q_w     = (const float*)d_in[2];
    const float* q_b     = (const float*)d_in[3];
    const float* k_w     = (const float*)d_in[4];
    const float* k_b     = (const float*)d_in[5];
    float* out = (float*)d_out;

    ushort_t* ft = (ushort_t*)d_ws;                       // [NTOK][CC] bf16
    ushort_t* qbuf = ft + (size_t)NTOK * CC;              // [NTOK][CC] bf16
    ushort_t* kbuf = qbuf + (size_t)NTOK * CC;            // [NTOK][CC] bf16
    ushort_t* wq = kbuf + (size_t)NTOK * CC;              // [CC][CC] bf16
    ushort_t* wk = wq + (size_t)CC * CC;
    float* den = (float*)(wk + (size_t)CC * CC);          // [NTOK]
    float* nx  = den + NTOK;
    float* ny  = nx + NTOK;

    hipMemsetAsync(den, 0, (size_t)3 * NTOK * sizeof(float), stream);
    wconv_kernel<<<32, 256, 0, stream>>>(q_w, k_w, wq, wk);
    tconv_kernel<<<1024, 256, 0, stream>>>(feature, ft);
    proj_kernel<<<512, 256, 0, stream>>>(ft, wq, wk, q_b, k_b, qbuf, kbuf);
    attn_kernel<<<1024, 256, 0, stream>>>(qbuf, kbuf, flow, den, nx, ny);
    finalize_kernel<<<64, 256, 0, stream>>>(den, nx, ny, out);
}

// Round 5
// 159.243 us; speedup vs baseline: 1.6847x; 1.2049x over previous
//
#include <hip/hip_runtime.h>
#include <math.h>

#define BB 4
#define CC 256
#define HWN 4096
#define NTOK 16384                 // BB*HWN
#define SCQ 0.09016844136f         // (1/sqrt(256)) * log2(e)

typedef __attribute__((ext_vector_type(8))) short short8;
typedef __attribute__((ext_vector_type(4))) float f32x4;
typedef unsigned short ushort_t;

__device__ __forceinline__ ushort_t f2bf(float f) {
    unsigned int u = __float_as_uint(f);
    unsigned int r = (u + 0x7FFFu + ((u >> 16) & 1u)) >> 16;   // RNE
    return (ushort_t)r;
}
__device__ __forceinline__ unsigned int pack2(float a, float b) {
    return (unsigned int)f2bf(a) | ((unsigned int)f2bf(b) << 16);
}

// ---------------------------------------------------------------------------
// Feature transpose [b][c][tok] fp32 -> ft[b*HW+tok][c] bf16, + zero the
// den/nx/ny accumulators (fused to save a launch).
// ---------------------------------------------------------------------------
__global__ __launch_bounds__(256) void tconv_kernel(
    const float* __restrict__ feature, ushort_t* __restrict__ ft,
    float* __restrict__ zbuf)
{
    int gid = blockIdx.x * 256 + threadIdx.x;
    if (gid < 3 * NTOK) zbuf[gid] = 0.f;

    int id = blockIdx.x;
    int tb = id & 63; id >>= 6;
    int cb = id & 3;  id >>= 2;
    int b  = id;
    int t = threadIdx.x;

    __shared__ float lt[64][68];

    const float* F = feature + ((size_t)(b * CC + cb * 64)) * HWN + tb * 64;
    int cl = t >> 2, tg = (t & 3) * 16;
    const float* src = F + (size_t)cl * HWN + tg;
    *(float4*)&lt[cl][tg]      = *(const float4*)(src);
    *(float4*)&lt[cl][tg + 4]  = *(const float4*)(src + 4);
    *(float4*)&lt[cl][tg + 8]  = *(const float4*)(src + 8);
    *(float4*)&lt[cl][tg + 12] = *(const float4*)(src + 12);
    __syncthreads();

    int tok = t >> 2, c16 = (t & 3) * 16;
    uint4 o0, o1;
    o0.x = pack2(lt[c16 + 0][tok],  lt[c16 + 1][tok]);
    o0.y = pack2(lt[c16 + 2][tok],  lt[c16 + 3][tok]);
    o0.z = pack2(lt[c16 + 4][tok],  lt[c16 + 5][tok]);
    o0.w = pack2(lt[c16 + 6][tok],  lt[c16 + 7][tok]);
    o1.x = pack2(lt[c16 + 8][tok],  lt[c16 + 9][tok]);
    o1.y = pack2(lt[c16 + 10][tok], lt[c16 + 11][tok]);
    o1.z = pack2(lt[c16 + 12][tok], lt[c16 + 13][tok]);
    o1.w = pack2(lt[c16 + 14][tok], lt[c16 + 15][tok]);
    ushort_t* O = ft + ((size_t)(b * HWN + tb * 64 + tok)) * CC + cb * 64 + c16;
    *(uint4*)&O[0] = o0;
    *(uint4*)&O[8] = o1;
}

// ---------------------------------------------------------------------------
// MFMA projection, fused weight convert (fp32->bf16 in-register, Q weights
// pre-scaled by (1/sqrt C)*log2e). Block = 64 tok x 64 d, grid 1024, no LDS.
// A = weight rows (m=d), B = token rows (n=tok); B-frags register-prefetched.
// ---------------------------------------------------------------------------
__global__ __launch_bounds__(256) void proj_kernel(
    const ushort_t* __restrict__ ft,
    const float* __restrict__ q_w, const float* __restrict__ k_w,
    const float* __restrict__ q_bias, const float* __restrict__ k_bias,
    ushort_t* __restrict__ qb, ushort_t* __restrict__ kb)
{
    int id = blockIdx.x;
    int tt = id & 255;             // 64-token tile (b folded in)
    int dh = id >> 8;              // d quarter
    int t = threadIdx.x, w = t >> 6, lane = t & 63;
    int n16 = lane & 15, quad = lane >> 4;
    int n0 = tt * 64;
    int d0 = dh * 64 + w * 16;

    short8 aq[8], ak[8];
    #pragma unroll
    for (int c = 0; c < 8; c++) {
        size_t off = (size_t)(d0 + n16) * CC + c * 32 + quad * 8;
        float4 a0 = *(const float4*)&q_w[off];
        float4 a1 = *(const float4*)&q_w[off + 4];
        short8 s;
        s[0] = (short)f2bf(a0.x * SCQ); s[1] = (short)f2bf(a0.y * SCQ);
        s[2] = (short)f2bf(a0.z * SCQ); s[3] = (short)f2bf(a0.w * SCQ);
        s[4] = (short)f2bf(a1.x * SCQ); s[5] = (short)f2bf(a1.y * SCQ);
        s[6] = (short)f2bf(a1.z * SCQ); s[7] = (short)f2bf(a1.w * SCQ);
        aq[c] = s;
        a0 = *(const float4*)&k_w[off];
        a1 = *(const float4*)&k_w[off + 4];
        s[0] = (short)f2bf(a0.x); s[1] = (short)f2bf(a0.y);
        s[2] = (short)f2bf(a0.z); s[3] = (short)f2bf(a0.w);
        s[4] = (short)f2bf(a1.x); s[5] = (short)f2bf(a1.y);
        s[6] = (short)f2bf(a1.z); s[7] = (short)f2bf(a1.w);
        ak[c] = s;
    }
    float bqv[4], bkv[4];
    #pragma unroll
    for (int r = 0; r < 4; r++) {
        bqv[r] = q_bias[d0 + quad * 4 + r] * SCQ;
        bkv[r] = k_bias[d0 + quad * 4 + r];
    }

    short8 bf[8], bf2[8];
    #pragma unroll
    for (int c = 0; c < 8; c++)
        bf[c] = *(const short8*)&ft[(size_t)(n0 + n16) * CC + c * 32 + quad * 8];

    #pragma unroll
    for (int bt = 0; bt < 4; bt++) {
        if (bt < 3) {
            #pragma unroll
            for (int c = 0; c < 8; c++)
                bf2[c] = *(const short8*)&ft[(size_t)(n0 + (bt + 1) * 16 + n16) * CC
                                             + c * 32 + quad * 8];
        }
        f32x4 cq = {0.f, 0.f, 0.f, 0.f};
        f32x4 ck = {0.f, 0.f, 0.f, 0.f};
        #pragma unroll
        for (int c = 0; c < 8; c++) {
            cq = __builtin_amdgcn_mfma_f32_16x16x32_bf16(aq[c], bf[c], cq, 0, 0, 0);
            ck = __builtin_amdgcn_mfma_f32_16x16x32_bf16(ak[c], bf[c], ck, 0, 0, 0);
        }
        size_t row = (size_t)(n0 + bt * 16 + n16) * CC + d0 + quad * 4;
        ushort4 oq, ok;
        oq.x = f2bf(cq[0] + bqv[0]); oq.y = f2bf(cq[1] + bqv[1]);
        oq.z = f2bf(cq[2] + bqv[2]); oq.w = f2bf(cq[3] + bqv[3]);
        ok.x = f2bf(ck[0] + bkv[0]); ok.y = f2bf(ck[1] + bkv[1]);
        ok.z = f2bf(ck[2] + bkv[2]); ok.w = f2bf(ck[3] + bkv[3]);
        *(ushort4*)&qb[row] = oq;
        *(ushort4*)&kb[row] = ok;
        #pragma unroll
        for (int c = 0; c < 8; c++) bf[c] = bf2[c];
    }
}

// ---------------------------------------------------------------------------
// Flash MFMA attention, double-buffered K staging.
// Block = (b, 128-q, 512-key range), 4 waves; grid ordered qt-fastest so
// 32 consecutive blocks share one K-range (per-XCD L2 reuse).
// 32-key LDS tiles (2 x 16 KB, XOR-swizzled) staged via global_load_lds;
// stage(k+1) issued before compute(k) -> vmcnt drain overlaps compute.
// Q pre-scaled by (1/16)*log2e => p = exp2(acc). No-max softmax => key-split
// additively exact via atomics.
// ---------------------------------------------------------------------------
__global__ __launch_bounds__(256, 3) void attn_kernel(
    const ushort_t* __restrict__ qb, const ushort_t* __restrict__ kb,
    const float* __restrict__ flow,
    float* __restrict__ den_g, float* __restrict__ nx_g, float* __restrict__ ny_g)
{
    int id = blockIdx.x;
    int qt = id & 31; id >>= 5;
    int sr = id & 7;  id >>= 3;
    int b = id;

    int t = threadIdx.x;
    int w = t >> 6, lane = t & 63;
    int n16 = lane & 15, quad = lane >> 4;

    int q0 = qt * 128 + w * 32;
    int s_beg = sr * 512;

    const ushort_t* Qb = qb + (size_t)b * HWN * CC;
    const ushort_t* Kb = kb + (size_t)b * HWN * CC;

    __shared__ __align__(16) ushort_t lk[2][8192];   // 2 x 16 KB swizzled K
    __shared__ float lflow[1024];

    const float* fx = flow + (size_t)b * 2 * HWN;
    const float* fy = fx + HWN;
    for (int j = t; j < 512; j += 256) {
        lflow[j]       = fx[s_beg + j];
        lflow[512 + j] = fy[s_beg + j];
    }

    short8 qf[2][8];
    #pragma unroll
    for (int tq = 0; tq < 2; tq++)
        #pragma unroll
        for (int c = 0; c < 8; c++)
            qf[tq][c] = *(const short8*)&Qb[(size_t)(q0 + tq * 16 + n16) * CC
                                            + c * 32 + quad * 8];

    // staging source offsets (XOR swizzle on 16B granules), loop-invariant
    int srcoff[4];
    #pragma unroll
    for (int i = 0; i < 4; i++) {
        int G = i * 256 + t;
        int r = G >> 5, j = G & 31;        // 32 rows x 32 granules
        srcoff[i] = (r * 32 + (j ^ r)) * 16;
    }
    int p16[8];
    #pragma unroll
    for (int c = 0; c < 8; c++)
        p16[c] = (((c * 4 + quad) ^ n16) & 31) * 16;

    float den[2][4], nxa[2][4], nya[2][4];
    #pragma unroll
    for (int tq = 0; tq < 2; tq++)
        #pragma unroll
        for (int r = 0; r < 4; r++) { den[tq][r] = 0.f; nxa[tq][r] = 0.f; nya[tq][r] = 0.f; }

    // prologue: stage tile 0 into buffer 0
    {
        const char* gsrc = (const char*)(Kb + (size_t)s_beg * CC);
        char* ldst = (char*)lk[0] + t * 16;
        #pragma unroll
        for (int i = 0; i < 4; i++)
            __builtin_amdgcn_global_load_lds(
                (const __attribute__((address_space(1))) unsigned int*)(gsrc + srcoff[i]),
                (__attribute__((address_space(3))) unsigned int*)(ldst + i * 4096),
                16, 0, 0);
    }

    for (int st = 0; st < 16; st++) {
        __syncthreads();   // buffer st&1 staged; prev reads of next buffer done
        if (st + 1 < 16) {
            const char* gsrc = (const char*)(Kb + (size_t)(s_beg + (st + 1) * 32) * CC);
            char* ldst = (char*)lk[(st + 1) & 1] + t * 16;
            #pragma unroll
            for (int i = 0; i < 4; i++)
                __builtin_amdgcn_global_load_lds(
                    (const __attribute__((address_space(1))) unsigned int*)(gsrc + srcoff[i]),
                    (__attribute__((address_space(3))) unsigned int*)(ldst + i * 4096),
                    16, 0, 0);
        }
        const char* base = (const char*)lk[st & 1];

        #pragma unroll
        for (int bt = 0; bt < 2; bt++) {
            int rbase = (bt * 16 + n16) * 512;
            int x16   = bt ? 256 : 0;
            f32x4 a0 = {0.f, 0.f, 0.f, 0.f};
            f32x4 a1 = {0.f, 0.f, 0.f, 0.f};
            #pragma unroll
            for (int c = 0; c < 8; c++) {
                short8 kf = *(const short8*)(base + rbase + (p16[c] ^ x16));
                a0 = __builtin_amdgcn_mfma_f32_16x16x32_bf16(qf[0][c], kf, a0, 0, 0, 0);
                a1 = __builtin_amdgcn_mfma_f32_16x16x32_bf16(qf[1][c], kf, a1, 0, 0, 0);
            }
            float vx = lflow[st * 32 + bt * 16 + n16];
            float vy = lflow[512 + st * 32 + bt * 16 + n16];
            #pragma unroll
            for (int r = 0; r < 4; r++) {
                float p0 = exp2f(a0[r]);
                float p1 = exp2f(a1[r]);
                den[0][r] += p0;                      den[1][r] += p1;
                nxa[0][r] = fmaf(p0, vx, nxa[0][r]);  nxa[1][r] = fmaf(p1, vx, nxa[1][r]);
                nya[0][r] = fmaf(p0, vy, nya[0][r]);  nya[1][r] = fmaf(p1, vy, nya[1][r]);
            }
        }
    }

    #pragma unroll
    for (int tq = 0; tq < 2; tq++)
        #pragma unroll
        for (int r = 0; r < 4; r++) {
            #pragma unroll
            for (int off = 8; off >= 1; off >>= 1) {
                den[tq][r] += __shfl_down(den[tq][r], off, 16);
                nxa[tq][r] += __shfl_down(nxa[tq][r], off, 16);
                nya[tq][r] += __shfl_down(nya[tq][r], off, 16);
            }
        }
    if (n16 == 0) {
        #pragma unroll
        for (int tq = 0; tq < 2; tq++)
            #pragma unroll
            for (int r = 0; r < 4; r++) {
                int qrow = q0 + tq * 16 + quad * 4 + r;
                int gi = b * HWN + qrow;
                atomicAdd(&den_g[gi], den[tq][r]);
                atomicAdd(&nx_g[gi],  nxa[tq][r]);
                atomicAdd(&ny_g[gi],  nya[tq][r]);
            }
    }
}

// ---------------------------------------------------------------------------
__global__ __launch_bounds__(256) void finalize_kernel(
    const float* __restrict__ den_g, const float* __restrict__ nx_g,
    const float* __restrict__ ny_g, float* __restrict__ out)
{
    int idx = blockIdx.x * 256 + threadIdx.x;  // b*HW + n
    int b = idx >> 12, n = idx & 4095;
    float inv = 1.0f / den_g[idx];
    out[(size_t)b * 2 * HWN + n]       = nx_g[idx] * inv;
    out[(size_t)b * 2 * HWN + HWN + n] = ny_g[idx] * inv;
}

extern "C" void kernel_launch(void* const* d_in, const int* in_sizes, int n_in,
                              void* d_out, int out_size, void* d_ws, size_t ws_size,
                              hipStream_t stream) {
    const float* feature = (const float*)d_in[0];
    const float* flow    = (const float*)d_in[1];
    const float* q_w     = (const float*)d_in[2];
    const float* q_b     = (const float*)d_in[3];
    const float* k_w     = (const float*)d_in[4];
    const float* k_b     = (const float*)d_in[5];
    float* out = (float*)d_out;

    ushort_t* ft   = (ushort_t*)d_ws;                     // [NTOK][CC] bf16
    ushort_t* qbuf = ft + (size_t)NTOK * CC;              // [NTOK][CC] bf16
    ushort_t* kbuf = qbuf + (size_t)NTOK * CC;            // [NTOK][CC] bf16
    float* den = (float*)(kbuf + (size_t)NTOK * CC);      // [NTOK]
    float* nx  = den + NTOK;
    float* ny  = nx + NTOK;

    tconv_kernel<<<1024, 256, 0, stream>>>(feature, ft, den);   // zeroes den/nx/ny
    proj_kernel<<<1024, 256, 0, stream>>>(ft, q_w, k_w, q_b, k_b, qbuf, kbuf);
    attn_kernel<<<1024, 256, 0, stream>>>(qbuf, kbuf, flow, den, nx, ny);
    finalize_kernel<<<64, 256, 0, stream>>>(den, nx, ny, out);
}